// Round 1
// baseline (5038.339 us; speedup 1.0000x reference)
//
#include <hip/hip_runtime.h>
#include <math.h>

#define NB    8
#define IMG   224
#define WIN   7
#define NTOK  (IMG*IMG)
#define DIM   96
#define NH    4
#define DHD   32
#define INR   128
#define HIDN  384
#define WT    49
#define EPSF  1e-5f
#define SCALE 0.17677669529663687f

#define FMA4(acc, hv, wv) \
    acc = fmaf((hv).x, (wv).x, fmaf((hv).y, (wv).y, fmaf((hv).z, (wv).z, fmaf((hv).w, (wv).w, (acc)))))

// ---------------- kernel 1: windowed attention (one block = one 7x7 window) ----------------
__global__ __launch_bounds__(256, 1) void win_attn_kernel(
    const float* __restrict__ x,
    const float* __restrict__ w_qkv,
    const float* __restrict__ w_out,
    const float* __restrict__ b_out,
    const float* __restrict__ rel_bias,
    const float* __restrict__ ln1_g,
    const float* __restrict__ ln1_b,
    float* __restrict__ y)
{
    // manual shared layout (floats): hs[49][96], qs/ks/vs[49][128], bias[169*4], mu/rs[49]
    __shared__ float smem[4704 + 3*6272 + 676 + 49 + 49];
    float* hs     = smem;                  // [49][96]  LN1 output
    float* qs     = smem + 4704;           // [49][128] q, later attention output o
    float* ks     = smem + 4704 + 6272;    // [49][128] k
    float* vs     = smem + 4704 + 2*6272;  // [49][128] v
    float* bias_s = smem + 4704 + 3*6272;  // [169][4]
    float* mu_s   = bias_s + 676;
    float* rs_s   = mu_s + WT;
    float* psum   = ks;                    // alias after attention: [2][49][96]

    const int tid = threadIdx.x;
    const int wid = blockIdx.x;
    const int b   = wid >> 10;
    const int xr  = (wid >> 5) & 31;
    const int yr  = wid & 31;

    for (int idx = tid; idx < 676; idx += 256) bias_s[idx] = rel_bias[idx];

    // load x window (49 x 96) into hs, float4
    for (int idx = tid; idx < WT * 24; idx += 256) {
        const int i = idx / 24, d4 = idx % 24;
        const int row = xr * WIN + i / WIN, col = yr * WIN + i % WIN;
        const size_t base = ((size_t)b * NTOK + (size_t)row * IMG + col) * DIM;
        *reinterpret_cast<float4*>(&hs[i * DIM + d4 * 4]) =
            *reinterpret_cast<const float4*>(x + base + d4 * 4);
    }
    __syncthreads();

    // LN1 stats (rotated c to break 96-stride bank alias)
    if (tid < WT) {
        float s = 0.f, s2 = 0.f;
        for (int cc = 0; cc < 24; ++cc) {
            const int c = (cc + tid) % 24;
            const float4 v = *reinterpret_cast<const float4*>(&hs[tid * DIM + c * 4]);
            s  += v.x + v.y + v.z + v.w;
            s2 += v.x * v.x + v.y * v.y + v.z * v.z + v.w * v.w;
        }
        const float m = s * (1.f / DIM);
        mu_s[tid] = m;
        rs_s[tid] = rsqrtf(s2 * (1.f / DIM) - m * m + EPSF);
    }
    __syncthreads();

    for (int idx = tid; idx < WT * DIM; idx += 256) {
        const int i = idx / DIM, d = idx % DIM;
        hs[idx] = (hs[idx] - mu_s[i]) * rs_s[i] * ln1_g[d] + ln1_b[d];
    }
    __syncthreads();

    // qkv GEMM: (49x96)@(96x384), column-owner, 49 accs/thread, LDS-broadcast h reads
    for (int pass = 0; pass < 2; ++pass) {
        const int o = pass * 256 + tid;
        if (o < 3 * INR) {
            float acc[WT];
            #pragma unroll
            for (int i = 0; i < WT; ++i) acc[i] = 0.f;
            const float4* wrow = reinterpret_cast<const float4*>(w_qkv + (size_t)o * DIM);
            for (int k4 = 0; k4 < DIM / 4; ++k4) {
                const float4 w = wrow[k4];
                #pragma unroll
                for (int i = 0; i < WT; ++i) {
                    const float4 hv = *reinterpret_cast<const float4*>(&hs[i * DIM + k4 * 4]);
                    FMA4(acc[i], hv, w);
                }
            }
            float* dst = (o < INR) ? &qs[o] : (o < 2 * INR) ? &ks[o - INR] : &vs[o - 2 * INR];
            #pragma unroll
            for (int i = 0; i < WT; ++i) dst[i * INR] = acc[i];
        }
    }
    __syncthreads();

    // attention: wave = head, lane = query row; scores fully in registers
    {
        const int h = tid >> 6;
        const int lane = tid & 63;
        if (lane < WT) {
            const int i = lane;
            float qreg[DHD];
            #pragma unroll
            for (int d = 0; d < DHD; ++d) qreg[d] = qs[i * INR + h * DHD + d];
            float sc[WT];
            const int ri = i / WIN, ci = i % WIN;
            #pragma unroll
            for (int j = 0; j < WT; ++j) {
                float dot = 0.f;
                #pragma unroll
                for (int d4 = 0; d4 < DHD / 4; ++d4) {
                    const float4 kf = *reinterpret_cast<const float4*>(&ks[j * INR + h * DHD + d4 * 4]);
                    dot = fmaf(qreg[d4 * 4 + 0], kf.x, dot);
                    dot = fmaf(qreg[d4 * 4 + 1], kf.y, dot);
                    dot = fmaf(qreg[d4 * 4 + 2], kf.z, dot);
                    dot = fmaf(qreg[d4 * 4 + 3], kf.w, dot);
                }
                const int rj = j / WIN, cj = j % WIN;
                const int bidx = (ri - rj + WIN - 1) * 13 + (ci - cj + WIN - 1);
                sc[j] = (dot + bias_s[bidx * NH + h]) * SCALE;  // bias added BEFORE scale, per ref
            }
            float mx = -1e30f;
            #pragma unroll
            for (int j = 0; j < WT; ++j) mx = fmaxf(mx, sc[j]);
            float l = 0.f;
            #pragma unroll
            for (int j = 0; j < WT; ++j) { sc[j] = __expf(sc[j] - mx); l += sc[j]; }
            const float inv = 1.f / l;
            float ov[DHD];
            #pragma unroll
            for (int d = 0; d < DHD; ++d) ov[d] = 0.f;
            #pragma unroll
            for (int j = 0; j < WT; ++j) {
                const float p = sc[j] * inv;
                #pragma unroll
                for (int d4 = 0; d4 < DHD / 4; ++d4) {
                    const float4 vf = *reinterpret_cast<const float4*>(&vs[j * INR + h * DHD + d4 * 4]);
                    ov[d4 * 4 + 0] = fmaf(p, vf.x, ov[d4 * 4 + 0]);
                    ov[d4 * 4 + 1] = fmaf(p, vf.y, ov[d4 * 4 + 1]);
                    ov[d4 * 4 + 2] = fmaf(p, vf.z, ov[d4 * 4 + 2]);
                    ov[d4 * 4 + 3] = fmaf(p, vf.w, ov[d4 * 4 + 3]);
                }
            }
            // safe overwrite of own q slot (only this lane ever reads/writes it)
            #pragma unroll
            for (int d = 0; d < DHD; ++d) qs[i * INR + h * DHD + d] = ov[d];
        }
    }
    __syncthreads();

    // output projection o(49x128) @ w_out^T(128x96), k-split halves; psum aliases ks/vs
    if (tid < 192) {
        const int half = tid / 96;
        const int d = tid - half * 96;
        float acc[WT];
        #pragma unroll
        for (int i = 0; i < WT; ++i) acc[i] = 0.f;
        const float4* wrow = reinterpret_cast<const float4*>(w_out + (size_t)d * INR + half * 64);
        for (int k4 = 0; k4 < 16; ++k4) {
            const float4 w = wrow[k4];
            const int kb = half * 64 + k4 * 4;
            #pragma unroll
            for (int i = 0; i < WT; ++i) {
                const float4 o4 = *reinterpret_cast<const float4*>(&qs[i * INR + kb]);
                FMA4(acc[i], o4, w);
            }
        }
        __syncthreads();  // all reads of qs/ks/vs done before psum overwrites ks/vs
        #pragma unroll
        for (int i = 0; i < WT; ++i) psum[half * 4704 + i * 96 + d] = acc[i];
    } else {
        __syncthreads();
    }
    __syncthreads();

    // combine + bias + residual (re-read x, L2-hot) -> scatter to y
    for (int idx = tid; idx < WT * DIM; idx += 256) {
        const int i = idx / DIM, d = idx % DIM;
        const int row = xr * WIN + i / WIN, col = yr * WIN + i % WIN;
        const size_t base = ((size_t)b * NTOK + (size_t)row * IMG + col) * DIM;
        y[base + d] = psum[i * 96 + d] + psum[4704 + i * 96 + d] + b_out[d] + x[base + d];
    }
}

// ---------------- kernel 2: LN2 + FFN, 32-token tiles, in-place on d_out ----------------
__global__ __launch_bounds__(256, 2) void ffn_kernel(
    float* __restrict__ yio,
    const float* __restrict__ ln2_g,
    const float* __restrict__ ln2_b,
    const float* __restrict__ w1,
    const float* __restrict__ b1,
    const float* __restrict__ w2,
    const float* __restrict__ b2)
{
    __shared__ float ys[32 * 96];
    __shared__ float h2[32 * 96];
    __shared__ float ts[32 * 384];   // GEMM1 output; reused as psum[2][32][96] after barrier
    __shared__ float mu[32], rs[32];

    const int tid = threadIdx.x;
    const size_t m0 = (size_t)blockIdx.x * 32;

    for (int idx = tid; idx < 32 * 24; idx += 256) {
        const int i = idx / 24, d4 = idx % 24;
        *reinterpret_cast<float4*>(&ys[i * 96 + d4 * 4]) =
            *reinterpret_cast<const float4*>(yio + (m0 + i) * DIM + d4 * 4);
    }
    __syncthreads();

    if (tid < 32) {
        float s = 0.f, s2 = 0.f;
        for (int cc = 0; cc < 24; ++cc) {
            const int c = (cc + tid) % 24;
            const float4 v = *reinterpret_cast<const float4*>(&ys[tid * 96 + c * 4]);
            s  += v.x + v.y + v.z + v.w;
            s2 += v.x * v.x + v.y * v.y + v.z * v.z + v.w * v.w;
        }
        const float m = s * (1.f / DIM);
        mu[tid] = m;
        rs[tid] = rsqrtf(s2 * (1.f / DIM) - m * m + EPSF);
    }
    __syncthreads();

    for (int idx = tid; idx < 32 * 96; idx += 256) {
        const int i = idx / 96, d = idx % 96;
        h2[idx] = (ys[idx] - mu[i]) * rs[i] * ln2_g[d] + ln2_b[d];
    }
    __syncthreads();

    // GEMM1: (32x96)@(96x384) + bias + exact GELU
    for (int pass = 0; pass < 2; ++pass) {
        const int o = pass * 256 + tid;
        if (o < HIDN) {
            float acc[32];
            #pragma unroll
            for (int i = 0; i < 32; ++i) acc[i] = 0.f;
            const float4* wrow = reinterpret_cast<const float4*>(w1 + (size_t)o * DIM);
            for (int k4 = 0; k4 < 24; ++k4) {
                const float4 w = wrow[k4];
                #pragma unroll
                for (int i = 0; i < 32; ++i) {
                    const float4 hv = *reinterpret_cast<const float4*>(&h2[i * 96 + k4 * 4]);
                    FMA4(acc[i], hv, w);
                }
            }
            const float bb = b1[o];
            #pragma unroll
            for (int i = 0; i < 32; ++i) {
                const float z = acc[i] + bb;
                ts[i * HIDN + o] = z * 0.5f * (1.f + erff(z * 0.70710678118654752f));
            }
        }
    }
    __syncthreads();

    // GEMM2: (32x384)@(384x96), k-split halves
    float acc2[32];
    int half = 0, d = 0;
    if (tid < 192) {
        half = tid / 96;
        d = tid - half * 96;
        #pragma unroll
        for (int i = 0; i < 32; ++i) acc2[i] = 0.f;
        const float4* wrow = reinterpret_cast<const float4*>(w2 + (size_t)d * HIDN + half * 192);
        for (int k4 = 0; k4 < 48; ++k4) {
            const float4 w = wrow[k4];
            const int kb = half * 192 + k4 * 4;
            #pragma unroll
            for (int i = 0; i < 32; ++i) {
                const float4 tv = *reinterpret_cast<const float4*>(&ts[i * HIDN + kb]);
                FMA4(acc2[i], tv, w);
            }
        }
    }
    __syncthreads();  // all ts reads complete
    if (tid < 192) {
        #pragma unroll
        for (int i = 0; i < 32; ++i) ts[half * 3072 + i * 96 + d] = acc2[i];
    }
    __syncthreads();

    for (int idx = tid; idx < 32 * 96; idx += 256) {
        const int i = idx / 96, dd = idx % 96;
        yio[(m0 + i) * DIM + idx % 96] = ts[i * 96 + dd] + ts[3072 + i * 96 + dd] + b2[dd] + ys[i * 96 + dd];
    }
}

extern "C" void kernel_launch(void* const* d_in, const int* in_sizes, int n_in,
                              void* d_out, int out_size, void* d_ws, size_t ws_size,
                              hipStream_t stream) {
    const float* x     = (const float*)d_in[0];
    const float* w_qkv = (const float*)d_in[1];
    const float* w_out = (const float*)d_in[2];
    const float* b_out = (const float*)d_in[3];
    const float* rel_b = (const float*)d_in[4];
    const float* ln1_g = (const float*)d_in[5];
    const float* ln1_b = (const float*)d_in[6];
    const float* ln2_g = (const float*)d_in[7];
    const float* ln2_b = (const float*)d_in[8];
    const float* w1    = (const float*)d_in[9];
    const float* b1    = (const float*)d_in[10];
    const float* w2    = (const float*)d_in[11];
    const float* b2    = (const float*)d_in[12];
    float* y = (float*)d_out;

    win_attn_kernel<<<NB * 32 * 32, 256, 0, stream>>>(x, w_qkv, w_out, b_out, rel_b, ln1_g, ln1_b, y);
    ffn_kernel<<<(NB * NTOK) / 32, 256, 0, stream>>>(y, ln2_g, ln2_b, w1, b1, w2, b2);
}

// Round 2
// 720.016 us; speedup vs baseline: 6.9975x; 6.9975x over previous
//
#include <hip/hip_runtime.h>
#include <math.h>

#define NB    8
#define IMG   224
#define NTOK  (IMG*IMG)          // 50176 per batch
#define DIM   96
#define INR   128
#define HIDN  384
#define WT    49
#define SCALE 0.17677669529663687f

typedef __attribute__((ext_vector_type(8))) short bf16x8;
typedef __attribute__((ext_vector_type(4))) float f32x4;

#define MFMA16(a,b,c) __builtin_amdgcn_mfma_f32_16x16x32_bf16((a),(b),(c),0,0,0)

__device__ __forceinline__ short f2bf(float f) {
    unsigned u = __builtin_bit_cast(unsigned, f);
    u += 0x7fffu + ((u >> 16) & 1u);
    return (short)(u >> 16);
}

// ---------- prep: convert weights to bf16, gather rel bias to [4][49][49] ----------
__global__ void prep_kernel(const float* __restrict__ wqkv, const float* __restrict__ wout,
                            const float* __restrict__ w1,   const float* __restrict__ w2,
                            const float* __restrict__ rel_bias, char* __restrict__ ws)
{
    short* wqkvb = (short*)ws;                 // 36864 elems
    short* woutb = (short*)(ws + 73728);       // 12288
    short* w1b   = (short*)(ws + 98304);       // 36864
    short* w2b   = (short*)(ws + 172032);      // 36864
    float* biasf = (float*)(ws + 245760);      // 9604 fp32
    const int idx = blockIdx.x * 256 + threadIdx.x;
    if      (idx < 36864)  wqkvb[idx]          = f2bf(wqkv[idx]);
    else if (idx < 49152)  woutb[idx - 36864]  = f2bf(wout[idx - 36864]);
    else if (idx < 86016)  w1b[idx - 49152]    = f2bf(w1[idx - 49152]);
    else if (idx < 122880) w2b[idx - 86016]    = f2bf(w2[idx - 86016]);
    else if (idx < 132484) {
        const int t = idx - 122880;
        const int h = t / 2401, r = t % 2401, i = r / 49, j = r % 49;
        const int rel = (i/7 - j/7 + 6) * 13 + (i%7 - j%7 + 6);
        biasf[t] = rel_bias[rel * 4 + h];
    }
}

// ---------- kernel 1: window attention via MFMA, one block = one 7x7 window ----------
// LDS pool (bytes): [0,25872) hs[64][104]bf16 then P[4][49][72]bf16 (aliased)
//                   [28224,45632) qs[64][136] (later os)
//                   [45632,63040) ks[64][136]
//                   [63040,81472) vt[128][72]
__global__ __launch_bounds__(256, 2) void attn_kernel(
    const float* __restrict__ x, const char* __restrict__ ws,
    const float* __restrict__ b_out, const float* __restrict__ ln1_g,
    const float* __restrict__ ln1_b, float* __restrict__ y)
{
    __shared__ __align__(16) char pool[81472];
    short* hs = (short*)pool;              // [64][104]
    short* Pm = (short*)pool;              // [4][49][72], aliases hs (hs dead by then)
    short* qs = (short*)(pool + 28224);    // [64][136], later os
    short* ks = (short*)(pool + 45632);    // [64][136]
    short* vt = (short*)(pool + 63040);    // [128][72]  (vt[dim][key])

    const short* wqkvb = (const short*)ws;
    const short* woutb = (const short*)(ws + 73728);
    const float* biasf = (const float*)(ws + 245760);

    const int tid = threadIdx.x;
    const int wv  = tid >> 6;         // wave 0..3
    const int l15 = tid & 15;
    const int l4  = (tid & 63) >> 4;
    const int wid = blockIdx.x;
    const int b = wid >> 10, xr = (wid >> 5) & 31, yr = wid & 31;

    // ---- LN1: 4 threads per row, values held in registers ----
    if (tid < 196) {
        const int i = tid >> 2, g = tid & 3;
        const float* xp = x + ((size_t)b * NTOK + (size_t)(xr*7 + i/7) * IMG + (yr*7 + i%7)) * DIM + g*24;
        float v[24]; float s = 0.f, s2 = 0.f;
        #pragma unroll
        for (int c = 0; c < 6; ++c) {
            const float4 t4 = *reinterpret_cast<const float4*>(xp + c*4);
            v[c*4+0]=t4.x; v[c*4+1]=t4.y; v[c*4+2]=t4.z; v[c*4+3]=t4.w;
            s  += t4.x + t4.y + t4.z + t4.w;
            s2 += t4.x*t4.x + t4.y*t4.y + t4.z*t4.z + t4.w*t4.w;
        }
        s  += __shfl_xor(s, 1);  s  += __shfl_xor(s, 2);
        s2 += __shfl_xor(s2, 1); s2 += __shfl_xor(s2, 2);
        const float mu = s * (1.f/96.f);
        const float rs = rsqrtf(s2 * (1.f/96.f) - mu*mu + 1e-5f);
        #pragma unroll
        for (int c = 0; c < 24; ++c) {
            const int d = g*24 + c;
            hs[i*104 + d] = f2bf((v[c] - mu) * rs * ln1_g[d] + ln1_b[d]);
        }
    }
    for (int idx = tid; idx < 15*104; idx += 256) hs[49*104 + idx] = 0;  // zero pad rows 49..63
    __syncthreads();

    // ---- qkv GEMM: h[64x96] @ Wqkv^T -> wave owns 96 output cols ----
    {
        bf16x8 afr[3][4];
        #pragma unroll
        for (int k3 = 0; k3 < 3; ++k3)
            #pragma unroll
            for (int mt = 0; mt < 4; ++mt)
                afr[k3][mt] = *reinterpret_cast<const bf16x8*>(&hs[(mt*16 + l15)*104 + k3*32 + l4*8]);
        f32x4 acc[6][4];
        #pragma unroll
        for (int nt = 0; nt < 6; ++nt)
            #pragma unroll
            for (int mt = 0; mt < 4; ++mt)
                acc[nt][mt] = (f32x4){0.f,0.f,0.f,0.f};
        #pragma unroll
        for (int nt = 0; nt < 6; ++nt) {
            const int o0 = wv*96 + nt*16;
            const short* wr = wqkvb + (size_t)(o0 + l15)*96 + l4*8;
            #pragma unroll
            for (int k3 = 0; k3 < 3; ++k3) {
                const bf16x8 bfr = *reinterpret_cast<const bf16x8*>(wr + k3*32);
                #pragma unroll
                for (int mt = 0; mt < 4; ++mt)
                    acc[nt][mt] = MFMA16(afr[k3][mt], bfr, acc[nt][mt]);
            }
        }
        #pragma unroll
        for (int nt = 0; nt < 6; ++nt) {
            const int o0 = wv*96 + nt*16;
            #pragma unroll
            for (int mt = 0; mt < 4; ++mt)
                #pragma unroll
                for (int rg = 0; rg < 4; ++rg) {
                    const int row = mt*16 + l4*4 + rg;
                    const short val = f2bf(acc[nt][mt][rg]);
                    if      (o0 < 128) qs[row*136 + o0 + l15]        = val;
                    else if (o0 < 256) ks[row*136 + o0 - 128 + l15]  = val;
                    else               vt[(o0 - 256 + l15)*72 + row] = val;
                }
        }
    }
    __syncthreads();

    // ---- S = Q K^T (per-head: wave = head), bias+scale+mask+softmax -> P (bf16) ----
    {
        bf16x8 aq[4], bk[4];
        #pragma unroll
        for (int mt = 0; mt < 4; ++mt)
            aq[mt] = *reinterpret_cast<const bf16x8*>(&qs[(mt*16 + l15)*136 + wv*32 + l4*8]);
        #pragma unroll
        for (int nt = 0; nt < 4; ++nt)
            bk[nt] = *reinterpret_cast<const bf16x8*>(&ks[(nt*16 + l15)*136 + wv*32 + l4*8]);
        f32x4 s[4][4];
        #pragma unroll
        for (int mt = 0; mt < 4; ++mt)
            #pragma unroll
            for (int nt = 0; nt < 4; ++nt)
                s[mt][nt] = MFMA16(aq[mt], bk[nt], ((f32x4){0.f,0.f,0.f,0.f}));

        #pragma unroll
        for (int mt = 0; mt < 4; ++mt) {
            #pragma unroll
            for (int rg = 0; rg < 4; ++rg) {
                const int i  = mt*16 + l4*4 + rg;
                const int ic = i < WT ? i : 48;
                float vals[4];
                #pragma unroll
                for (int nt = 0; nt < 4; ++nt) {
                    const int j  = nt*16 + l15;
                    const int jc = j < WT ? j : 48;
                    const float bb = biasf[(wv*49 + ic)*49 + jc];
                    const float sv = (s[mt][nt][rg] + bb) * SCALE;
                    vals[nt] = (j < WT) ? sv : -1e30f;
                }
                float mx = fmaxf(fmaxf(vals[0], vals[1]), fmaxf(vals[2], vals[3]));
                mx = fmaxf(mx, __shfl_xor(mx, 1)); mx = fmaxf(mx, __shfl_xor(mx, 2));
                mx = fmaxf(mx, __shfl_xor(mx, 4)); mx = fmaxf(mx, __shfl_xor(mx, 8));
                float sum = 0.f;
                #pragma unroll
                for (int nt = 0; nt < 4; ++nt) { vals[nt] = __expf(vals[nt] - mx); sum += vals[nt]; }
                sum += __shfl_xor(sum, 1); sum += __shfl_xor(sum, 2);
                sum += __shfl_xor(sum, 4); sum += __shfl_xor(sum, 8);
                const float inv = 1.f / sum;
                if (i < WT) {
                    #pragma unroll
                    for (int nt = 0; nt < 4; ++nt)
                        Pm[(wv*49 + i)*72 + nt*16 + l15] = f2bf(vals[nt] * inv);
                }
            }
        }
    }
    // in-wave LDS ordering suffices (P and os column-ranges are wave-private)

    // ---- PV: o = P @ V  (A=P from LDS, B=vt contiguous) -> os (aliases qs cols wv*32..) ----
    {
        f32x4 o[2][4];
        #pragma unroll
        for (int nt = 0; nt < 2; ++nt)
            #pragma unroll
            for (int mt = 0; mt < 4; ++mt)
                o[nt][mt] = (f32x4){0.f,0.f,0.f,0.f};
        #pragma unroll
        for (int kst = 0; kst < 2; ++kst) {
            bf16x8 bv[2];
            #pragma unroll
            for (int nt = 0; nt < 2; ++nt)
                bv[nt] = *reinterpret_cast<const bf16x8*>(&vt[(wv*32 + nt*16 + l15)*72 + kst*32 + l4*8]);
            #pragma unroll
            for (int mt = 0; mt < 4; ++mt) {
                const int rr = (mt*16 + l15) < WT ? (mt*16 + l15) : 48;   // clamp: stay in real P rows
                const bf16x8 ap = *reinterpret_cast<const bf16x8*>(&Pm[(wv*49 + rr)*72 + kst*32 + l4*8]);
                #pragma unroll
                for (int nt = 0; nt < 2; ++nt)
                    o[nt][mt] = MFMA16(ap, bv[nt], o[nt][mt]);
            }
        }
        #pragma unroll
        for (int nt = 0; nt < 2; ++nt)
            #pragma unroll
            for (int mt = 0; mt < 4; ++mt)
                #pragma unroll
                for (int rg = 0; rg < 4; ++rg)
                    qs[(mt*16 + l4*4 + rg)*136 + wv*32 + nt*16 + l15] = f2bf(o[nt][mt][rg]);
    }
    __syncthreads();

    // ---- proj: os[64x128] @ Wout^T + b_out + x -> y (wave = M-tile) ----
    {
        bf16x8 afr[4];
        #pragma unroll
        for (int kst = 0; kst < 4; ++kst)
            afr[kst] = *reinterpret_cast<const bf16x8*>(&qs[(wv*16 + l15)*136 + kst*32 + l4*8]);
        #pragma unroll
        for (int nt = 0; nt < 6; ++nt) {
            f32x4 acc = (f32x4){0.f,0.f,0.f,0.f};
            const short* wr = woutb + (size_t)(nt*16 + l15)*128 + l4*8;
            #pragma unroll
            for (int kst = 0; kst < 4; ++kst)
                acc = MFMA16(afr[kst], *reinterpret_cast<const bf16x8*>(wr + kst*32), acc);
            const float bo = b_out[nt*16 + l15];
            #pragma unroll
            for (int rg = 0; rg < 4; ++rg) {
                const int t = wv*16 + l4*4 + rg;
                if (t < WT) {
                    const size_t gi = ((size_t)b * NTOK + (size_t)(xr*7 + t/7) * IMG + (yr*7 + t%7)) * DIM + nt*16 + l15;
                    y[gi] = acc[rg] + bo + x[gi];
                }
            }
        }
    }
}

// ---------- kernel 2: LN2 + FFN via MFMA, 64-token tiles, 8 waves ----------
__global__ __launch_bounds__(512, 4) void ffn_kernel(
    float* __restrict__ y, const char* __restrict__ ws,
    const float* __restrict__ ln2_g, const float* __restrict__ ln2_b,
    const float* __restrict__ b1, const float* __restrict__ b2)
{
    __shared__ __align__(16) char pool[63488];
    short* h = (short*)pool;              // [64][104]
    short* t = (short*)(pool + 13312);    // [64][392]
    const short* w1b = (const short*)(ws + 98304);
    const short* w2b = (const short*)(ws + 172032);

    const int tid = threadIdx.x;
    const int wv  = tid >> 6;
    const int l15 = tid & 15;
    const int l4  = (tid & 63) >> 4;
    const size_t m0 = (size_t)blockIdx.x * 64;

    // ---- LN2: 8 threads per row ----
    {
        const int i = tid >> 3, g = tid & 7;
        const float* yp = y + (m0 + i) * DIM + g*12;
        float v[12]; float s = 0.f, s2 = 0.f;
        #pragma unroll
        for (int c = 0; c < 3; ++c) {
            const float4 t4 = *reinterpret_cast<const float4*>(yp + c*4);
            v[c*4+0]=t4.x; v[c*4+1]=t4.y; v[c*4+2]=t4.z; v[c*4+3]=t4.w;
            s  += t4.x + t4.y + t4.z + t4.w;
            s2 += t4.x*t4.x + t4.y*t4.y + t4.z*t4.z + t4.w*t4.w;
        }
        s  += __shfl_xor(s, 1);  s  += __shfl_xor(s, 2);  s  += __shfl_xor(s, 4);
        s2 += __shfl_xor(s2, 1); s2 += __shfl_xor(s2, 2); s2 += __shfl_xor(s2, 4);
        const float mu = s * (1.f/96.f);
        const float rs = rsqrtf(s2 * (1.f/96.f) - mu*mu + 1e-5f);
        #pragma unroll
        for (int c = 0; c < 12; ++c) {
            const int d = g*12 + c;
            h[i*104 + d] = f2bf((v[c] - mu) * rs * ln2_g[d] + ln2_b[d]);
        }
    }
    __syncthreads();

    // ---- GEMM1 + exact GELU: wave = (mt, N-half) ----
    {
        const int mt = wv >> 1, nh = wv & 1;
        bf16x8 afr[3];
        #pragma unroll
        for (int k3 = 0; k3 < 3; ++k3)
            afr[k3] = *reinterpret_cast<const bf16x8*>(&h[(mt*16 + l15)*104 + k3*32 + l4*8]);
        #pragma unroll
        for (int nt = 0; nt < 12; ++nt) {
            const int o0 = nh*192 + nt*16;
            f32x4 acc = (f32x4){0.f,0.f,0.f,0.f};
            const short* wr = w1b + (size_t)(o0 + l15)*96 + l4*8;
            #pragma unroll
            for (int k3 = 0; k3 < 3; ++k3)
                acc = MFMA16(afr[k3], *reinterpret_cast<const bf16x8*>(wr + k3*32), acc);
            const float bb = b1[o0 + l15];
            #pragma unroll
            for (int rg = 0; rg < 4; ++rg) {
                const float z = acc[rg] + bb;
                t[(mt*16 + l4*4 + rg)*392 + o0 + l15] = f2bf(z * 0.5f * (1.f + erff(z * 0.70710678118654752f)));
            }
        }
    }
    __syncthreads();

    // ---- GEMM2 + bias + residual: wave = (mt, N-third-pair) ----
    {
        const int mt = wv >> 1, np = wv & 1;
        bf16x8 afr[12];
        #pragma unroll
        for (int kst = 0; kst < 12; ++kst)
            afr[kst] = *reinterpret_cast<const bf16x8*>(&t[(mt*16 + l15)*392 + kst*32 + l4*8]);
        #pragma unroll
        for (int nt = 0; nt < 3; ++nt) {
            const int d0 = np*48 + nt*16;
            f32x4 acc = (f32x4){0.f,0.f,0.f,0.f};
            const short* wr = w2b + (size_t)(d0 + l15)*384 + l4*8;
            #pragma unroll
            for (int kst = 0; kst < 12; ++kst)
                acc = MFMA16(afr[kst], *reinterpret_cast<const bf16x8*>(wr + kst*32), acc);
            const float bb = b2[d0 + l15];
            #pragma unroll
            for (int rg = 0; rg < 4; ++rg) {
                const size_t gi = (m0 + mt*16 + l4*4 + rg) * DIM + d0 + l15;
                y[gi] = acc[rg] + bb + y[gi];
            }
        }
    }
}

extern "C" void kernel_launch(void* const* d_in, const int* in_sizes, int n_in,
                              void* d_out, int out_size, void* d_ws, size_t ws_size,
                              hipStream_t stream) {
    const float* x     = (const float*)d_in[0];
    const float* w_qkv = (const float*)d_in[1];
    const float* w_out = (const float*)d_in[2];
    const float* b_out = (const float*)d_in[3];
    const float* rel_b = (const float*)d_in[4];
    const float* ln1_g = (const float*)d_in[5];
    const float* ln1_b = (const float*)d_in[6];
    const float* ln2_g = (const float*)d_in[7];
    const float* ln2_b = (const float*)d_in[8];
    const float* w1    = (const float*)d_in[9];
    const float* b1    = (const float*)d_in[10];
    const float* w2    = (const float*)d_in[11];
    const float* b2    = (const float*)d_in[12];
    float* y = (float*)d_out;
    char* ws = (char*)d_ws;

    prep_kernel<<<518, 256, 0, stream>>>(w_qkv, w_out, w1, w2, rel_b, ws);
    attn_kernel<<<NB * 32 * 32, 256, 0, stream>>>(x, ws, b_out, ln1_g, ln1_b, y);
    ffn_kernel<<<(NB * NTOK) / 64, 512, 0, stream>>>(y, ws, ln2_g, ln2_b, b1, b2);
}